// Round 4
// baseline (455.498 us; speedup 1.0000x reference)
//
#include <hip/hip_runtime.h>

#define BB 8
#define CC_ALL 128
#define HH 160
#define WW 160
#define PAD 4
#define RANGE 9
#define ND 80
#define NG 9                  // one disparity row per block
#define TH 8                  // tile: full-width 160 x 8
#define NTX 40
#define PXT 4
#define NTHREADS 320          // 5 waves
#define CCHUNK 4
#define NROWS TH              // DR=1: 8 f2 rows cover the tile
#define ROWF (WW + 2 * PAD)   // 168
#define PLANE (HH * WW)
#define NSLOT (CCHUNK * NROWS * (WW / 4) / NTHREADS)  // 4 float4 slots/thread
#define NACC (RANGE * PXT)    // 36

__global__ __launch_bounds__(NTHREADS, 5)
void cost_volume_kernel(const float* __restrict__ f1,
                        const float* __restrict__ f2,
                        float* __restrict__ out) {
    __shared__ __align__(16) float s2[CCHUNK][NROWS][ROWF];

    const int tile_y = blockIdx.x;              // 0..19
    const int bz     = blockIdx.y;              // 0..71
    const int b = bz / NG;
    const int g = bz - b * NG;                  // di row 0..8
    const int h0 = tile_y * TH;
    const int tid = threadIdx.x;
    const int tx = tid % NTX;
    const int ty = tid / NTX;
    const int w = tx * PXT;
    const int h = h0 + ty;
    const int row_start = h0 + g - PAD;         // image row of LDS row 0

    // zero LDS once: pad cols + OOB rows stay zero
    {
        float* p = &s2[0][0][0];
        for (int i = tid; i < CCHUNK * NROWS * ROWF; i += NTHREADS) p[i] = 0.f;
    }

    // precompute channel-invariant staging slots
    int glb_off[NSLOT];
    int lds_off[NSLOT];
    unsigned vmask = 0;
#pragma unroll
    for (int k = 0; k < NSLOT; k++) {
        const int s = tid + k * NTHREADS;
        const int quad = s % (WW / 4);
        const int t = s / (WW / 4);
        const int row = t % NROWS;
        const int cc = t / NROWS;
        const int gh = row_start + row;
        glb_off[k] = cc * PLANE + gh * WW + quad * 4;
        lds_off[k] = (cc * NROWS + row) * ROWF + PAD + quad * 4;
        if ((unsigned)gh < HH) vmask |= (1u << k);
    }

    float acc[NACC];
#pragma unroll
    for (int i = 0; i < NACC; i++) acc[i] = 0.f;

    const float* f1p = f1 + (size_t)b * CC_ALL * PLANE + (size_t)h * WW + w;
    const float* f2b = f2 + (size_t)b * CC_ALL * PLANE;
    float* s2f = &s2[0][0][0];

    for (int c0 = 0; c0 < CC_ALL; c0 += CCHUNK) {
        __syncthreads();   // protect LDS from previous chunk's readers
#pragma unroll
        for (int k = 0; k < NSLOT; k++) {
            if (vmask & (1u << k)) {
                const float4 v = *(const float4*)(f2b + (size_t)c0 * PLANE + glb_off[k]);
                *(float4*)(s2f + lds_off[k]) = v;
            }
        }
        __syncthreads();

#pragma unroll
        for (int cc = 0; cc < CCHUNK; cc++) {
            const float4 a = *(const float4*)(f1p + (size_t)(c0 + cc) * PLANE);
            const float av[PXT] = {a.x, a.y, a.z, a.w};
            // LDS row ty holds image row h + g - 4 (this block's single di row)
            const float* rp = &s2[cc][ty][w];   // lds col w = image col w-4
            float win[12];
            *(float4*)&win[0] = *(const float4*)(rp);
            *(float4*)&win[4] = *(const float4*)(rp + 4);
            *(float4*)&win[8] = *(const float4*)(rp + 8);
#pragma unroll
            for (int dj = 0; dj < RANGE; dj++) {
#pragma unroll
                for (int p = 0; p < PXT; p++) {
                    acc[dj * PXT + p] += av[p] * win[dj + p];
                }
            }
        }
    }

    // epilogue: mean, skip center lin==40
    float* ob = out + (size_t)b * ND * PLANE + (size_t)h * WW + w;
#pragma unroll
    for (int dj = 0; dj < RANGE; dj++) {
        const int lin = g * RANGE + dj;
        if (lin == 40) continue;                // block-uniform
        const int d = lin - (lin > 40 ? 1 : 0);
        float4 o;
        o.x = acc[dj * PXT + 0] * (1.f / 128.f);
        o.y = acc[dj * PXT + 1] * (1.f / 128.f);
        o.z = acc[dj * PXT + 2] * (1.f / 128.f);
        o.w = acc[dj * PXT + 3] * (1.f / 128.f);
        *(float4*)(ob + (size_t)d * PLANE) = o;
    }
}

extern "C" void kernel_launch(void* const* d_in, const int* in_sizes, int n_in,
                              void* d_out, int out_size, void* d_ws, size_t ws_size,
                              hipStream_t stream) {
    const float* feat1 = (const float*)d_in[0];
    const float* feat2 = (const float*)d_in[1];
    float* out = (float*)d_out;

    dim3 grid(HH / TH, BB * NG);   // 20 x 72 = 1440 blocks
    dim3 block(NTHREADS);
    cost_volume_kernel<<<grid, block, 0, stream>>>(feat1, feat2, out);
}